// Round 2
// baseline (1210.728 us; speedup 1.0000x reference)
//
#include <hip/hip_runtime.h>
#include <math.h>

#define NNODES 50000
#define NEDGES 800000
#define INC 512
#define OUTC 256
#define DECD 256
#define NMASK 25000

// ---------------- degree / CSR construction ----------------

__global__ void count_deg_k(const int* __restrict__ dst, int* __restrict__ deg) {
    int e = blockIdx.x * blockDim.x + threadIdx.x;
    if (e < NEDGES) atomicAdd(&deg[dst[e]], 1);
}

__global__ void dinv_k(const int* __restrict__ deg, float* __restrict__ dinv) {
    int n = blockIdx.x * blockDim.x + threadIdx.x;
    if (n < NNODES) dinv[n] = rsqrtf((float)deg[n] + 1.0f);  // +1 self-loop
}

// single-block exclusive scan over 50000 degree counts -> CSR offsets (+cursor copy)
__global__ __launch_bounds__(1024) void scan_k(const int* __restrict__ deg,
                                               int* __restrict__ offs,
                                               int* __restrict__ cursor) {
    __shared__ int sd[1024];
    __shared__ int carry_s;
    int tid = threadIdx.x;
    if (tid == 0) carry_s = 0;
    __syncthreads();
    for (int base = 0; base < NNODES; base += 1024) {
        int i = base + tid;
        int v = (i < NNODES) ? deg[i] : 0;
        sd[tid] = v;
        __syncthreads();
        for (int off = 1; off < 1024; off <<= 1) {
            int t = (tid >= off) ? sd[tid - off] : 0;
            __syncthreads();
            sd[tid] += t;
            __syncthreads();
        }
        int incl = sd[tid];
        int carry = carry_s;
        __syncthreads();           // all reads of carry_s done before update
        if (i < NNODES) {
            int ex = carry + incl - v;
            offs[i] = ex;
            cursor[i] = ex;
        }
        if (tid == 1023) carry_s = carry + incl;
        __syncthreads();
    }
    if (tid == 0) offs[NNODES] = carry_s;   // == NEDGES
}

__global__ void fill_csr_k(const int* __restrict__ src, const int* __restrict__ dst,
                           const float* __restrict__ dinv, int* __restrict__ cursor,
                           int* __restrict__ ssrc, float* __restrict__ coef) {
    int e = blockIdx.x * blockDim.x + threadIdx.x;
    if (e >= NEDGES) return;
    int s = src[e], d = dst[e];
    int pos = atomicAdd(&cursor[d], 1);
    ssrc[pos] = s;
    coef[pos] = dinv[s] * dinv[d];
}

// ---------------- small helpers ----------------

// token_h[j] = sum_k mask_token[k] * enc_W[k][j]   (1 block x 256 threads)
__global__ void token_k(const float* __restrict__ token, const float* __restrict__ W,
                        float* __restrict__ outv) {
    int j = threadIdx.x;
    float s = 0.f;
    for (int k = 0; k < INC; ++k) s += token[k] * W[(size_t)k * OUTC + j];
    outv[j] = s;
}

// overwrite masked rows of h1 with token_h (one wave per masked row)
__global__ __launch_bounds__(64) void maskfix_k(const int* __restrict__ idx,
                                                const float* __restrict__ tokh,
                                                float* __restrict__ h1) {
    int r = idx[blockIdx.x];
    int t = threadIdx.x;
    *(float4*)(h1 + (size_t)r * OUTC + t * 4) = *(const float4*)(tokh + t * 4);
}

__global__ void copy4_k(const float4* __restrict__ in, float4* __restrict__ out, int n4) {
    int i = blockIdx.x * blockDim.x + threadIdx.x;
    if (i < n4) out[i] = in[i];
}

// mask indices written as float values (harness reads flat out buffer as f32)
__global__ void maskout_k(const int* __restrict__ idx, float* __restrict__ out) {
    int i = blockIdx.x * blockDim.x + threadIdx.x;
    if (i < NMASK) out[i] = (float)idx[i];
}

// ---------------- fp32 tiled GEMM: C[M,N] = A[M,K] @ B[K,N] (+bias) ----------------
// BM=BN=64, BK=16, 256 threads, 4x4 micro-tile per thread.

__global__ __launch_bounds__(256) void sgemm_k(const float* __restrict__ A,
                                               const float* __restrict__ B,
                                               float* __restrict__ C,
                                               int M, int K, int N,
                                               const float* __restrict__ bias) {
    __shared__ float As[16][64];   // As[k][m]
    __shared__ float Bs[16][64];   // Bs[k][n]
    const int t  = threadIdx.x;
    const int tx = t & 15, ty = t >> 4;
    const int bm = blockIdx.y * 64;
    const int bn = blockIdx.x * 64;
    const int arow = t >> 2;          // 0..63
    const int akc  = (t & 3) * 4;     // 0,4,8,12
    const int bkr  = t >> 4;          // 0..15
    const int bnc  = (t & 15) * 4;
    float acc[4][4] = {};

    for (int k0 = 0; k0 < K; k0 += 16) {
        float4 av = make_float4(0.f, 0.f, 0.f, 0.f);
        int grow = bm + arow;
        if (grow < M) av = *(const float4*)(A + (size_t)grow * K + k0 + akc);
        As[akc + 0][arow] = av.x;
        As[akc + 1][arow] = av.y;
        As[akc + 2][arow] = av.z;
        As[akc + 3][arow] = av.w;
        *(float4*)&Bs[bkr][bnc] = *(const float4*)(B + (size_t)(k0 + bkr) * N + bn + bnc);
        __syncthreads();
#pragma unroll
        for (int k = 0; k < 16; ++k) {
            float4 a = *(const float4*)&As[k][ty * 4];
            float4 b = *(const float4*)&Bs[k][tx * 4];
            acc[0][0] += a.x * b.x; acc[0][1] += a.x * b.y; acc[0][2] += a.x * b.z; acc[0][3] += a.x * b.w;
            acc[1][0] += a.y * b.x; acc[1][1] += a.y * b.y; acc[1][2] += a.y * b.z; acc[1][3] += a.y * b.w;
            acc[2][0] += a.z * b.x; acc[2][1] += a.z * b.y; acc[2][2] += a.z * b.z; acc[2][3] += a.z * b.w;
            acc[3][0] += a.w * b.x; acc[3][1] += a.w * b.y; acc[3][2] += a.w * b.z; acc[3][3] += a.w * b.w;
        }
        __syncthreads();
    }

#pragma unroll
    for (int i = 0; i < 4; ++i) {
        int grow = bm + ty * 4 + i;
        if (grow >= M) continue;
        float4 v = make_float4(acc[i][0], acc[i][1], acc[i][2], acc[i][3]);
        if (bias) {
            v.x += bias[bn + tx * 4 + 0];
            v.y += bias[bn + tx * 4 + 1];
            v.z += bias[bn + tx * 4 + 2];
            v.w += bias[bn + tx * 4 + 3];
        }
        *(float4*)(C + (size_t)grow * N + bn + tx * 4) = v;
    }
}

// ---------------- GCN aggregation: one wave per node, 256 channels ----------------
// out[d][:] = sum_{e: dst=d} h[src_e][:]*coef_e + h[d][:]*dinv[d]^2 + bias  (opt relu)

__global__ __launch_bounds__(64) void agg_k(const float* __restrict__ h,
                                            float* __restrict__ out,
                                            const float* __restrict__ bias,
                                            const float* __restrict__ dinv,
                                            const int* __restrict__ offs,
                                            const int* __restrict__ ssrc,
                                            const float* __restrict__ coef,
                                            int do_relu) {
    int node = blockIdx.x;
    int t = threadIdx.x;                 // 64 threads x float4 = 256 channels
    int beg = offs[node], end = offs[node + 1];
    float4 acc = make_float4(0.f, 0.f, 0.f, 0.f);
    for (int e = beg; e < end; ++e) {
        int s = ssrc[e];
        float c = coef[e];
        float4 v = *(const float4*)(h + (size_t)s * OUTC + t * 4);
        acc.x += v.x * c; acc.y += v.y * c; acc.z += v.z * c; acc.w += v.w * c;
    }
    float di = dinv[node];
    float sc = di * di;
    float4 hv = *(const float4*)(h + (size_t)node * OUTC + t * 4);
    float4 bv = *(const float4*)(bias + t * 4);
    acc.x += hv.x * sc + bv.x;
    acc.y += hv.y * sc + bv.y;
    acc.z += hv.z * sc + bv.z;
    acc.w += hv.w * sc + bv.w;
    if (do_relu) {
        acc.x = fmaxf(acc.x, 0.f); acc.y = fmaxf(acc.y, 0.f);
        acc.z = fmaxf(acc.z, 0.f); acc.w = fmaxf(acc.w, 0.f);
    }
    *(float4*)(out + (size_t)node * OUTC + t * 4) = acc;
}

// ---------------- launch ----------------

extern "C" void kernel_launch(void* const* d_in, const int* in_sizes, int n_in,
                              void* d_out, int out_size, void* d_ws, size_t ws_size,
                              hipStream_t stream) {
    const float* x    = (const float*)d_in[0];
    const int*   eidx = (const int*)d_in[1];
    const int*   midx = (const int*)d_in[2];
    const float* mtok = (const float*)d_in[3];
    const float* encW = (const float*)d_in[4];
    const float* encB = (const float*)d_in[5];
    const float* decW = (const float*)d_in[6];
    const float* decB = (const float*)d_in[7];
    const float* mlpW = (const float*)d_in[8];
    const float* mlpB = (const float*)d_in[9];
    const int* srcs = eidx;            // edge_index[0]
    const int* dsts = eidx + NEDGES;   // edge_index[1]

    char* ws = (char*)d_ws;
    float* bufA  = (float*)(ws + 0);            // 50000*256*4 = 51,200,000
    float* bufB  = (float*)(ws + 51200000);     // 51,200,000
    int*   deg   = (int*)  (ws + 102400000);    // 200,000
    float* dinv  = (float*)(ws + 102600000);    // 200,000
    int*   offs  = (int*)  (ws + 102800000);    // 200,004 (padded to 200,064)
    int*   cursor= (int*)  (ws + 103000064);    // 200,000
    int*   ssrc  = (int*)  (ws + 103200064);    // 3,200,000
    float* coef  = (float*)(ws + 106400064);    // 3,200,000
    float* tokh  = (float*)(ws + 109600064);    // 1,024

    float* out_recon = (float*)d_out;                          // [50000,512]
    float* out_x     = out_recon + (size_t)NNODES * INC;       // [50000,512]
    float* out_mask  = out_x + (size_t)NNODES * INC;           // [25000] as f32

    hipMemsetAsync(deg, 0, NNODES * sizeof(int), stream);
    count_deg_k<<<(NEDGES + 255) / 256, 256, 0, stream>>>(dsts, deg);
    dinv_k<<<(NNODES + 255) / 256, 256, 0, stream>>>(deg, dinv);
    scan_k<<<1, 1024, 0, stream>>>(deg, offs, cursor);
    fill_csr_k<<<(NEDGES + 255) / 256, 256, 0, stream>>>(srcs, dsts, dinv, cursor, ssrc, coef);

    token_k<<<1, 256, 0, stream>>>(mtok, encW, tokh);

    // encoder GEMM: h1 = x @ enc_W  (masked rows fixed up after)
    sgemm_k<<<dim3(OUTC / 64, (NNODES + 63) / 64), 256, 0, stream>>>(
        x, encW, bufA, NNODES, INC, OUTC, nullptr);
    maskfix_k<<<NMASK, 64, 0, stream>>>(midx, tokh, bufA);

    // z = agg(h1) + h1*dinv^2 + enc_b
    agg_k<<<NNODES, 64, 0, stream>>>(bufA, bufB, encB, dinv, offs, ssrc, coef, 0);

    // decoder GEMM: h2 = z @ dec_W
    sgemm_k<<<dim3(DECD / 64, (NNODES + 63) / 64), 256, 0, stream>>>(
        bufB, decW, bufA, NNODES, OUTC, DECD, nullptr);

    // h = relu(agg(h2) + h2*dinv^2 + dec_b)
    agg_k<<<NNODES, 64, 0, stream>>>(bufA, bufB, decB, dinv, offs, ssrc, coef, 1);

    // x_recon = h @ mlp_W + mlp_b  -> directly into d_out
    sgemm_k<<<dim3(INC / 64, (NNODES + 63) / 64), 256, 0, stream>>>(
        bufB, mlpW, out_recon, NNODES, DECD, INC, mlpB);

    // outputs 1 and 2
    copy4_k<<<(NNODES * INC / 4 + 255) / 256, 256, 0, stream>>>(
        (const float4*)x, (float4*)out_x, NNODES * INC / 4);
    maskout_k<<<(NMASK + 255) / 256, 256, 0, stream>>>(midx, out_mask);
}

// Round 3
// 796.761 us; speedup vs baseline: 1.5196x; 1.5196x over previous
//
#include <hip/hip_runtime.h>
#include <math.h>

#define NNODES 50000
#define NEDGES 800000
#define INC 512
#define OUTC 256
#define DECD 256
#define NMASK 25000

typedef __attribute__((ext_vector_type(8))) short short8;
typedef __attribute__((ext_vector_type(4))) float f32x4;

__device__ __forceinline__ unsigned short f2bf(float f) {
    unsigned int u = __float_as_uint(f);
    u = (u + 0x7fff + ((u >> 16) & 1)) >> 16;   // RNE
    return (unsigned short)u;
}
__device__ __forceinline__ float bf2f(unsigned short u) {
    return __uint_as_float(((unsigned int)u) << 16);
}

// ---------------- degree / CSR construction ----------------

__global__ void count_deg_k(const int* __restrict__ dst, int* __restrict__ deg) {
    int e = blockIdx.x * blockDim.x + threadIdx.x;
    if (e < NEDGES) atomicAdd(&deg[dst[e]], 1);
}

__global__ void dinv_k(const int* __restrict__ deg, float* __restrict__ dinv) {
    int n = blockIdx.x * blockDim.x + threadIdx.x;
    if (n < NNODES) dinv[n] = rsqrtf((float)deg[n] + 1.0f);  // +1 self-loop
}

__global__ __launch_bounds__(1024) void scan_k(const int* __restrict__ deg,
                                               int* __restrict__ offs,
                                               int* __restrict__ cursor) {
    __shared__ int sd[1024];
    __shared__ int carry_s;
    int tid = threadIdx.x;
    if (tid == 0) carry_s = 0;
    __syncthreads();
    for (int base = 0; base < NNODES; base += 1024) {
        int i = base + tid;
        int v = (i < NNODES) ? deg[i] : 0;
        sd[tid] = v;
        __syncthreads();
        for (int off = 1; off < 1024; off <<= 1) {
            int t = (tid >= off) ? sd[tid - off] : 0;
            __syncthreads();
            sd[tid] += t;
            __syncthreads();
        }
        int incl = sd[tid];
        int carry = carry_s;
        __syncthreads();
        if (i < NNODES) {
            int ex = carry + incl - v;
            offs[i] = ex;
            cursor[i] = ex;
        }
        if (tid == 1023) carry_s = carry + incl;
        __syncthreads();
    }
    if (tid == 0) offs[NNODES] = carry_s;
}

__global__ void fill_csr_k(const int* __restrict__ src, const int* __restrict__ dst,
                           const float* __restrict__ dinv, int* __restrict__ cursor,
                           int* __restrict__ ssrc, float* __restrict__ coef) {
    int e = blockIdx.x * blockDim.x + threadIdx.x;
    if (e >= NEDGES) return;
    int s = src[e], d = dst[e];
    int pos = atomicAdd(&cursor[d], 1);
    ssrc[pos] = s;
    coef[pos] = dinv[s] * dinv[d];
}

// ---------------- conversions ----------------

// f32 -> bf16 elementwise, 4 at a time
__global__ void cvt_bf_k(const float4* __restrict__ in, ushort4* __restrict__ out, int n4) {
    int i = blockIdx.x * blockDim.x + threadIdx.x;
    if (i >= n4) return;
    float4 v = in[i];
    ushort4 u;
    u.x = f2bf(v.x); u.y = f2bf(v.y); u.z = f2bf(v.z); u.w = f2bf(v.w);
    out[i] = u;
}

// W[K][N] f32 -> Wt[N][K] bf16 (coalesced writes)
__global__ void wt_k(const float* __restrict__ W, unsigned short* __restrict__ Wt,
                     int K, int N) {
    int o = blockIdx.x * blockDim.x + threadIdx.x;
    if (o >= K * N) return;
    int n = o / K;
    int k = o - n * K;
    Wt[o] = f2bf(W[(size_t)k * N + n]);
}

// token_h[j] = sum_k mask_token[k] * enc_W[k][j]  (fp32)
__global__ void token_k(const float* __restrict__ token, const float* __restrict__ W,
                        float* __restrict__ outv) {
    int j = threadIdx.x;
    float s = 0.f;
    for (int k = 0; k < INC; ++k) s += token[k] * W[(size_t)k * OUTC + j];
    outv[j] = s;
}

// overwrite masked rows of h1(bf16) with token_h
__global__ __launch_bounds__(64) void maskfix_bf_k(const int* __restrict__ idx,
                                                   const float* __restrict__ tokh,
                                                   unsigned short* __restrict__ h1) {
    int r = idx[blockIdx.x];
    int t = threadIdx.x;
    float4 v = *(const float4*)(tokh + t * 4);
    ushort4 u;
    u.x = f2bf(v.x); u.y = f2bf(v.y); u.z = f2bf(v.z); u.w = f2bf(v.w);
    *(ushort4*)(h1 + (size_t)r * OUTC + t * 4) = u;
}

__global__ void copy4_k(const float4* __restrict__ in, float4* __restrict__ out, int n4) {
    int i = blockIdx.x * blockDim.x + threadIdx.x;
    if (i < n4) out[i] = in[i];
}

__global__ void maskout_k(const int* __restrict__ idx, float* __restrict__ out) {
    int i = blockIdx.x * blockDim.x + threadIdx.x;
    if (i < NMASK) out[i] = (float)idx[i];
}

// ---------------- bf16 MFMA GEMM ----------------
// C[M,N] = A[M,K](bf16) @ Bt[N,K](bf16)^T  (+bias), C fp32 or bf16.
// 128x128 tile, BK=32, 256 threads = 4 waves (2x2 of 64x64), 16x16x32 MFMA.
// Staging via global_load_lds width=16 into unpadded [128][32] bf16 LDS tiles.

__global__ __launch_bounds__(256) void gemm_bf16_k(const unsigned short* __restrict__ A,
                                                   const unsigned short* __restrict__ Bt,
                                                   void* __restrict__ Cout,
                                                   int M, int K, int N,
                                                   const float* __restrict__ bias,
                                                   int out_bf16) {
    __shared__ unsigned short As[128 * 32];   // 8 KB
    __shared__ unsigned short Bs[128 * 32];   // 8 KB
    const int t = threadIdx.x;
    const int lane = t & 63, wv = t >> 6;
    const int bm = blockIdx.y * 128;
    const int bn = blockIdx.x * 128;
    const int wm = (wv >> 1) * 64, wn = (wv & 1) * 64;
    const int lr = lane & 15, lq = lane >> 4;

    f32x4 acc[4][4] = {};

    // per-round staging chunk indices (16B chunks over [128][32] bf16 tile)
    for (int k0 = 0; k0 < K; k0 += 32) {
        __syncthreads();
#pragma unroll
        for (int r = 0; r < 2; ++r) {
            int idx = r * 256 + wv * 64 + lane;   // 0..511
            int row = idx >> 2;                   // 0..127
            int c8 = (idx & 3) * 8;               // 0,8,16,24
            int ga = bm + row;
            if (ga >= M) ga = M - 1;              // clamp tail (stores guarded)
            const unsigned short* gA = A + (size_t)ga * K + k0 + c8;
            const unsigned short* gB = Bt + (size_t)(bn + row) * K + k0 + c8;
            __builtin_amdgcn_global_load_lds(
                (const __attribute__((address_space(1))) unsigned int*)gA,
                (__attribute__((address_space(3))) unsigned int*)&As[(r * 256 + wv * 64) * 8],
                16, 0, 0);
            __builtin_amdgcn_global_load_lds(
                (const __attribute__((address_space(1))) unsigned int*)gB,
                (__attribute__((address_space(3))) unsigned int*)&Bs[(r * 256 + wv * 64) * 8],
                16, 0, 0);
        }
        __syncthreads();

        short8 av[4], bv[4];
#pragma unroll
        for (int mt = 0; mt < 4; ++mt)
            av[mt] = *(const short8*)&As[(wm + mt * 16 + lr) * 32 + lq * 8];
#pragma unroll
        for (int nt = 0; nt < 4; ++nt)
            bv[nt] = *(const short8*)&Bs[(wn + nt * 16 + lr) * 32 + lq * 8];
#pragma unroll
        for (int mt = 0; mt < 4; ++mt)
#pragma unroll
            for (int nt = 0; nt < 4; ++nt)
                acc[mt][nt] = __builtin_amdgcn_mfma_f32_16x16x32_bf16(
                    av[mt], bv[nt], acc[mt][nt], 0, 0, 0);
    }

    // epilogue: D[row][col], col = lane&15, row = (lane>>4)*4 + reg
    float* Cf = (float*)Cout;
    unsigned short* Cb = (unsigned short*)Cout;
#pragma unroll
    for (int nt = 0; nt < 4; ++nt) {
        int col = bn + wn + nt * 16 + lr;
        float bv_ = bias ? bias[col] : 0.f;
#pragma unroll
        for (int mt = 0; mt < 4; ++mt) {
            int row0 = bm + wm + mt * 16 + lq * 4;
#pragma unroll
            for (int reg = 0; reg < 4; ++reg) {
                int row = row0 + reg;
                if (row >= M) continue;
                float v = acc[mt][nt][reg] + bv_;
                if (out_bf16) Cb[(size_t)row * N + col] = f2bf(v);
                else          Cf[(size_t)row * N + col] = v;
            }
        }
    }
}

// ---------------- GCN aggregation (bf16 in/out, fp32 accum) ----------------

__global__ __launch_bounds__(64) void agg_bf_k(const unsigned short* __restrict__ h,
                                               unsigned short* __restrict__ out,
                                               const float* __restrict__ bias,
                                               const float* __restrict__ dinv,
                                               const int* __restrict__ offs,
                                               const int* __restrict__ ssrc,
                                               const float* __restrict__ coef,
                                               int do_relu) {
    int node = blockIdx.x;
    int t = threadIdx.x;                 // 64 threads x 4 ch = 256 channels
    int beg = offs[node], end = offs[node + 1];
    float a0 = 0.f, a1 = 0.f, a2 = 0.f, a3 = 0.f;
    for (int e = beg; e < end; ++e) {
        int s = ssrc[e];
        float c = coef[e];
        ushort4 v = *(const ushort4*)(h + (size_t)s * OUTC + t * 4);
        a0 += bf2f(v.x) * c; a1 += bf2f(v.y) * c;
        a2 += bf2f(v.z) * c; a3 += bf2f(v.w) * c;
    }
    float di = dinv[node];
    float sc = di * di;
    ushort4 hv = *(const ushort4*)(h + (size_t)node * OUTC + t * 4);
    float4 bv = *(const float4*)(bias + t * 4);
    a0 += bf2f(hv.x) * sc + bv.x;
    a1 += bf2f(hv.y) * sc + bv.y;
    a2 += bf2f(hv.z) * sc + bv.z;
    a3 += bf2f(hv.w) * sc + bv.w;
    if (do_relu) {
        a0 = fmaxf(a0, 0.f); a1 = fmaxf(a1, 0.f);
        a2 = fmaxf(a2, 0.f); a3 = fmaxf(a3, 0.f);
    }
    ushort4 u;
    u.x = f2bf(a0); u.y = f2bf(a1); u.z = f2bf(a2); u.w = f2bf(a3);
    *(ushort4*)(out + (size_t)node * OUTC + t * 4) = u;
}

// ---------------- launch ----------------

extern "C" void kernel_launch(void* const* d_in, const int* in_sizes, int n_in,
                              void* d_out, int out_size, void* d_ws, size_t ws_size,
                              hipStream_t stream) {
    const float* x    = (const float*)d_in[0];
    const int*   eidx = (const int*)d_in[1];
    const int*   midx = (const int*)d_in[2];
    const float* mtok = (const float*)d_in[3];
    const float* encW = (const float*)d_in[4];
    const float* encB = (const float*)d_in[5];
    const float* decW = (const float*)d_in[6];
    const float* decB = (const float*)d_in[7];
    const float* mlpW = (const float*)d_in[8];
    const float* mlpB = (const float*)d_in[9];
    const int* srcs = eidx;
    const int* dsts = eidx + NEDGES;

    char* ws = (char*)d_ws;
    unsigned short* x_bf  = (unsigned short*)(ws + 0);            // 51,200,000
    unsigned short* hA_bf = (unsigned short*)(ws + 51200000);     // 25,600,000 (GEMM outs)
    unsigned short* hB_bf = (unsigned short*)(ws + 76800000);     // 25,600,000 (agg outs)
    int*   deg    = (int*)  (ws + 102400000);
    float* dinv   = (float*)(ws + 102600000);
    int*   offs   = (int*)  (ws + 102800000);
    int*   cursor = (int*)  (ws + 103000064);
    int*   ssrc   = (int*)  (ws + 103200064);    // 3,200,000
    float* coef   = (float*)(ws + 106400064);    // 3,200,000
    float* tokh   = (float*)(ws + 109600064);    // 1,024
    unsigned short* encWt = (unsigned short*)(ws + 109601088);    // 262,144
    unsigned short* decWt = (unsigned short*)(ws + 109863232);    // 131,072
    unsigned short* mlpWt = (unsigned short*)(ws + 109994304);    // 262,144

    float* out_recon = (float*)d_out;
    float* out_x     = out_recon + (size_t)NNODES * INC;
    float* out_mask  = out_x + (size_t)NNODES * INC;

    hipMemsetAsync(deg, 0, NNODES * sizeof(int), stream);
    count_deg_k<<<(NEDGES + 255) / 256, 256, 0, stream>>>(dsts, deg);
    dinv_k<<<(NNODES + 255) / 256, 256, 0, stream>>>(deg, dinv);
    scan_k<<<1, 1024, 0, stream>>>(deg, offs, cursor);
    fill_csr_k<<<(NEDGES + 255) / 256, 256, 0, stream>>>(srcs, dsts, dinv, cursor, ssrc, coef);

    token_k<<<1, 256, 0, stream>>>(mtok, encW, tokh);

    // conversions
    cvt_bf_k<<<(NNODES * INC / 4 + 255) / 256, 256, 0, stream>>>(
        (const float4*)x, (ushort4*)x_bf, NNODES * INC / 4);
    wt_k<<<(INC * OUTC + 255) / 256, 256, 0, stream>>>(encW, encWt, INC, OUTC);
    wt_k<<<(OUTC * DECD + 255) / 256, 256, 0, stream>>>(decW, decWt, OUTC, DECD);
    wt_k<<<(DECD * INC + 255) / 256, 256, 0, stream>>>(mlpW, mlpWt, DECD, INC);

    // encoder GEMM: h1 = x @ enc_W  (bf16 out), then mask fixup
    gemm_bf16_k<<<dim3(OUTC / 128, (NNODES + 127) / 128), 256, 0, stream>>>(
        x_bf, encWt, hA_bf, NNODES, INC, OUTC, nullptr, 1);
    maskfix_bf_k<<<NMASK, 64, 0, stream>>>(midx, tokh, hA_bf);

    // z = agg(h1) + h1*dinv^2 + enc_b  (bf16 out)
    agg_bf_k<<<NNODES, 64, 0, stream>>>(hA_bf, hB_bf, encB, dinv, offs, ssrc, coef, 0);

    // decoder GEMM: h2 = z @ dec_W (bf16 out)
    gemm_bf16_k<<<dim3(DECD / 128, (NNODES + 127) / 128), 256, 0, stream>>>(
        hB_bf, decWt, hA_bf, NNODES, OUTC, DECD, nullptr, 1);

    // h = relu(agg(h2) + h2*dinv^2 + dec_b) (bf16 out)
    agg_bf_k<<<NNODES, 64, 0, stream>>>(hA_bf, hB_bf, decB, dinv, offs, ssrc, coef, 1);

    // x_recon = h @ mlp_W + mlp_b -> fp32 directly to d_out
    gemm_bf16_k<<<dim3(INC / 128, (NNODES + 127) / 128), 256, 0, stream>>>(
        hB_bf, mlpWt, out_recon, NNODES, DECD, INC, mlpB, 0);

    // outputs 1 and 2
    copy4_k<<<(NNODES * INC / 4 + 255) / 256, 256, 0, stream>>>(
        (const float4*)x, (float4*)out_x, NNODES * INC / 4);
    maskout_k<<<(NMASK + 255) / 256, 256, 0, stream>>>(midx, out_mask);
}